// Round 8
// baseline (12882.787 us; speedup 1.0000x reference)
//
#include <hip/hip_runtime.h>

typedef short short8 __attribute__((ext_vector_type(8)));
typedef float f32x4 __attribute__((ext_vector_type(4)));
typedef unsigned short u16;

#define Bz   32
#define Sz   512
#define DIN  512
#define DH   1024
#define DOUT 512
#define KTOT 1536
#define NWG  128
#define NTH  512
#define TPW  12      // k-tiles (of 32) per k-split wave; 4 kwid x 12 = 48 = KTOT/32

// ---- bf16 split helpers (RNE) ----
__device__ __forceinline__ u16 bf_rne(float f) {
  unsigned b = __float_as_uint(f);
  return (u16)((b + 0x7fffu + ((b >> 16) & 1u)) >> 16);
}
__device__ __forceinline__ float bf_f(u16 h) { return __uint_as_float(((unsigned)h) << 16); }
__device__ __forceinline__ void bf_split(float f, u16& hi, u16& lo) {
  hi = bf_rne(f);
  lo = bf_rne(f - bf_f(hi));
}

__device__ __forceinline__ float sigm(float v) { return 1.0f / (1.0f + __expf(-v)); }

__device__ __forceinline__ f32x4 mfma16(short8 a, short8 b, f32x4 c) {
  return __builtin_amdgcn_mfma_f32_16x16x32_bf16(a, b, c, 0, 0, 0);
}

// ---- single-hop all-to-all flag barrier ----
// Each wg release-stores the round into its own 128B-padded flag; every wg
// polls ALL flags directly (thread tid < NWG polls flag[tid]) — no central
// release hop. Relaxed spins (no per-poll cache maintenance) + one agent
// ACQUIRE fence after detection. Happens-before: producer h-stores -> release
// flag store (wbL2) -> consumer observes flag -> acquire fence (inv) ->
// post-barrier h loads pull fresh lines from L3.
__device__ __forceinline__ void grid_bar(unsigned* __restrict__ arrive,
                                         int wg, int tid, unsigned round) {
  __syncthreads();
  if (tid == 0)
    __hip_atomic_store(&arrive[wg * 32], round, __ATOMIC_RELEASE,
                       __HIP_MEMORY_SCOPE_AGENT);
  if (tid < NWG) {
    while (__hip_atomic_load(&arrive[tid * 32], __ATOMIC_RELAXED,
                             __HIP_MEMORY_SCOPE_AGENT) < round)
      __builtin_amdgcn_s_sleep(2);
  }
  __builtin_amdgcn_fence(__ATOMIC_ACQUIRE, "agent");
  __syncthreads();
}

// ---- x fp32 -> (hi, lo) bf16 split, layout-preserving [B][S][DIN] ----
__global__ __launch_bounds__(256)
void xsplit(const float* __restrict__ x, u16* __restrict__ xhi, u16* __restrict__ xlo) {
  const int i = (blockIdx.x * 256 + threadIdx.x) * 4;   // grid sized exactly
  const float4 v = *(const float4*)(x + i);
  u16 h0, l0, h1, l1, h2, l2, h3, l3;
  bf_split(v.x, h0, l0); bf_split(v.y, h1, l1);
  bf_split(v.z, h2, l2); bf_split(v.w, h3, l3);
  ushort4 hv = {h0, h1, h2, h3}, lv = {l0, l1, l2, l3};
  *(ushort4*)(xhi + i) = hv;
  *(ushort4*)(xlo + i) = lv;
}

// ---- persistent LSTM recurrence: 128 wgs x 512 thr (8 waves) ----
// wg owns 32 gate-interleaved columns = 2 n-subgroups x 16 (c = 4*j + g).
// Wave wid: nsub = wid>>2 (which 16-col group), kwid = wid&3 (k-split).
// Wave holds its 12 k-tiles of W as register B-frags (hi/lo bf16, 96 VGPR).
// A-frags load straight from global. K-reduction across kwid via 16 KB LDS.
__global__ __launch_bounds__(NTH, 1)
void lstm_rec(const u16* __restrict__ xhi, const u16* __restrict__ xlo,
              const float* __restrict__ Wf, const float* __restrict__ bfv,
              const float* __restrict__ Wi, const float* __restrict__ biv,
              const float* __restrict__ Wg, const float* __restrict__ bgv,
              const float* __restrict__ Wo, const float* __restrict__ bov,
              u16* __restrict__ hhi, u16* __restrict__ hlo,   // [2][Bz][DH] each
              float* __restrict__ hs,                         // [Bz][Sz][DH]
              unsigned* __restrict__ arrive)
{
  __shared__ __align__(16) float pdump[8][2][64][4];  // [wave][mtile][lane][reg] 16 KB
  __shared__ float csh[Bz][8];                        // c-state, persistent
  __shared__ float bsh[32];

  const int tid  = threadIdx.x;
  const int wg   = blockIdx.x;
  const int wid  = tid >> 6;
  const int lane = tid & 63;
  const int kwid = wid & 3;         // k-split index (12 k-tiles each)
  const int nsub = wid >> 2;        // n-subgroup (16 gate-cols each)
  const int c    = lane & 15;       // gate-col within subgroup: g = c&3, j = c>>2
  const int q    = lane >> 4;       // k-subgroup (8 k each)
  const int g    = c & 3;
  const int jl   = c >> 2;
  const int col  = wg * 8 + nsub * 4 + jl;   // hidden column

  // ---- one-time: W slice -> register B-frags, hi/lo split ----
  const float* Wsrc = (g == 0) ? Wf : (g == 1) ? Wi : (g == 2) ? Wg : Wo;
  short8 Bhi[TPW], Blo[TPW];
  #pragma unroll
  for (int tt = 0; tt < TPW; ++tt) {
    const int k0 = (kwid * TPW + tt) * 32 + q * 8;
    short8 bh, bl;
    #pragma unroll
    for (int i = 0; i < 8; ++i) {
      u16 h, l;
      bf_split(Wsrc[(k0 + i) * DH + col], h, l);
      bh[i] = (short)h; bl[i] = (short)l;
    }
    Bhi[tt] = bh; Blo[tt] = bl;
  }
  if (tid < 32) {
    const int g2 = tid & 3;
    const float* bsrc = (g2 == 0) ? bfv : (g2 == 1) ? biv : (g2 == 2) ? bgv : bov;
    bsh[tid] = bsrc[wg * 8 + (tid >> 2)];
  }
  if (tid < 256) {
    csh[tid & 31][tid >> 5] = 0.0f;
    const int idx = wg * 256 + tid;   // zero h0 (buffer 0): 32768 entries / 128 wgs
    hhi[idx] = 0; hlo[idx] = 0;
  }
  grid_bar(arrive, wg, tid, 1u);

  const int bA = lane & 15;           // A-frag row = batch (m=0: bA, m=1: bA+16)

  for (int t = 0; t < Sz; ++t) {
    const u16* __restrict__ hh = hhi + (t & 1) * (Bz * DH);
    const u16* __restrict__ hl = hlo + (t & 1) * (Bz * DH);

    f32x4 a_hh0 = {0.f,0.f,0.f,0.f}, a_hl0 = a_hh0, a_lh0 = a_hh0;
    f32x4 a_hh1 = a_hh0, a_hl1 = a_hh0, a_lh1 = a_hh0;

    #pragma unroll
    for (int tt = 0; tt < TPW; ++tt) {
      const int k = (kwid * TPW + tt) * 32 + q * 8;
      short8 Ah0, Al0, Ah1, Al1;
      if (k < DIN) {                   // x part of comb
        Ah0 = *(const short8*)(xhi + ((bA * Sz + t) * DIN + k));
        Ah1 = *(const short8*)(xhi + (((bA + 16) * Sz + t) * DIN + k));
        Al0 = *(const short8*)(xlo + ((bA * Sz + t) * DIN + k));
        Al1 = *(const short8*)(xlo + (((bA + 16) * Sz + t) * DIN + k));
      } else {                         // h part of comb
        const int kh = k - DIN;
        Ah0 = *(const short8*)(hh + bA * DH + kh);
        Ah1 = *(const short8*)(hh + (bA + 16) * DH + kh);
        Al0 = *(const short8*)(hl + bA * DH + kh);
        Al1 = *(const short8*)(hl + (bA + 16) * DH + kh);
      }
      a_hh0 = mfma16(Ah0, Bhi[tt], a_hh0);   // 3-term bf16x3 product, 6 indep chains
      a_hl0 = mfma16(Ah0, Blo[tt], a_hl0);
      a_lh0 = mfma16(Al0, Bhi[tt], a_lh0);
      a_hh1 = mfma16(Ah1, Bhi[tt], a_hh1);
      a_hl1 = mfma16(Ah1, Blo[tt], a_hl1);
      a_lh1 = mfma16(Al1, Bhi[tt], a_lh1);
    }
    const f32x4 acc0 = a_hh0 + a_hl0 + a_lh0;
    const f32x4 acc1 = a_hh1 + a_hl1 + a_lh1;
    *(f32x4*)&pdump[wid][0][lane][0] = acc0;
    *(f32x4*)&pdump[wid][1][lane][0] = acc1;
    __syncthreads();

    if (tid < 256) {                   // pointwise: thread -> (b, jj)
      const int b = tid & 31, jj = tid >> 5;         // jj 0..7
      const int m = b >> 4, r = b & 15, rg = r & 3;
      const int ns = jj >> 2, ji = jj & 3;
      float G[4];
      #pragma unroll
      for (int g2 = 0; g2 < 4; ++g2) {
        const int ln = (r >> 2) * 16 + (ji * 4 + g2); // D: col=lane&15, row=(lane>>4)*4+reg
        G[g2] = bsh[jj * 4 + g2]
              + pdump[ns * 4 + 0][m][ln][rg] + pdump[ns * 4 + 1][m][ln][rg]
              + pdump[ns * 4 + 2][m][ln][rg] + pdump[ns * 4 + 3][m][ln][rg];
      }
      const float fv = sigm(G[0]);
      const float iv = sigm(G[1]);
      const float gv = tanhf(G[2]);
      const float ov = sigm(G[3]);
      const float cn = fv * csh[b][jj] + iv * gv;
      csh[b][jj] = cn;
      const float hv = ov * tanhf(cn);
      u16 hx, lx; bf_split(hv, hx, lx);
      const int par = ((t + 1) & 1) * (Bz * DH);
      hhi[par + b * DH + wg * 8 + jj] = hx;
      hlo[par + b * DH + wg * 8 + jj] = lx;
      hs[(b * Sz + t) * DH + wg * 8 + jj] = hv;
    }
    grid_bar(arrive, wg, tid, (unsigned)(t + 2));
  }
}

// ---- final FC: [16384,1024] @ [1024,512] + bias, fp32, 64x64 tile, 4x4 micro ----
__global__ __launch_bounds__(256)
void lstm_fc(const float* __restrict__ hs, const float* __restrict__ Wfc,
             const float* __restrict__ bfc, float* __restrict__ out)
{
  __shared__ __align__(16) float Ash[16][68];
  __shared__ __align__(16) float Bsh[16][68];
  const int tid = threadIdx.x;
  const int mt = (int)(blockIdx.x >> 3) * 64;
  const int nt = (int)(blockIdx.x & 7) * 64;
  const int ty = tid >> 4, tx = tid & 15;
  const int am = tid & 63, ak = (tid >> 6) * 4;
  const int bk = tid >> 4, bn = (tid & 15) * 4;
  float acc[4][4] = {};
  for (int k0 = 0; k0 < DH; k0 += 16) {
    const float4 av = *(const float4*)&hs[(mt + am) * DH + k0 + ak];
    const float4 bv = *(const float4*)&Wfc[(k0 + bk) * DOUT + nt + bn];
    Ash[ak + 0][am] = av.x;
    Ash[ak + 1][am] = av.y;
    Ash[ak + 2][am] = av.z;
    Ash[ak + 3][am] = av.w;
    *(float4*)&Bsh[bk][bn] = bv;
    __syncthreads();
    #pragma unroll
    for (int kk = 0; kk < 16; ++kk) {
      const float4 a = *(const float4*)&Ash[kk][ty * 4];
      const float4 b = *(const float4*)&Bsh[kk][tx * 4];
      const float avv[4] = {a.x, a.y, a.z, a.w};
      const float bvv[4] = {b.x, b.y, b.z, b.w};
      #pragma unroll
      for (int i = 0; i < 4; ++i)
        #pragma unroll
        for (int j = 0; j < 4; ++j)
          acc[i][j] = fmaf(avv[i], bvv[j], acc[i][j]);
    }
    __syncthreads();
  }
  const float4 bb = *(const float4*)&bfc[nt + tx * 4];
  const float bias[4] = {bb.x, bb.y, bb.z, bb.w};
  #pragma unroll
  for (int i = 0; i < 4; ++i) {
    float4 o;
    o.x = acc[i][0] + bias[0];
    o.y = acc[i][1] + bias[1];
    o.z = acc[i][2] + bias[2];
    o.w = acc[i][3] + bias[3];
    *(float4*)&out[(mt + ty * 4 + i) * DOUT + nt + tx * 4] = o;
  }
}

extern "C" void kernel_launch(void* const* d_in, const int* in_sizes, int n_in,
                              void* d_out, int out_size, void* d_ws, size_t ws_size,
                              hipStream_t stream) {
  const float* x   = (const float*)d_in[0];
  const float* Wf  = (const float*)d_in[1];
  const float* bf  = (const float*)d_in[2];
  const float* Wi  = (const float*)d_in[3];
  const float* bi  = (const float*)d_in[4];
  const float* Wg  = (const float*)d_in[5];
  const float* bg  = (const float*)d_in[6];
  const float* Wo  = (const float*)d_in[7];
  const float* bo  = (const float*)d_in[8];
  const float* Wfc = (const float*)d_in[9];
  const float* bfc = (const float*)d_in[10];
  float* out = (float*)d_out;

  // ws layout: [0,16K) arrive flags (128B-padded, 128 wgs) | 64K: data
  char* w = (char*)d_ws;
  unsigned* arrive = (unsigned*)w;
  size_t off = 65536;
  u16* hhi = (u16*)(w + off);                         off += 2u * Bz * DH * sizeof(u16);
  u16* hlo = (u16*)(w + off);                         off += 2u * Bz * DH * sizeof(u16);
  u16* xhi = (u16*)(w + off);                         off += (size_t)Bz * Sz * DIN * sizeof(u16);
  u16* xlo = (u16*)(w + off);                         off += (size_t)Bz * Sz * DIN * sizeof(u16);
  float* hs = (float*)(w + off);

  hipMemsetAsync(d_ws, 0, 65536, stream);             // zero all barrier flags

  const int xN = Bz * Sz * DIN;                       // 8,388,608 (exactly 8192*256*4)
  hipLaunchKernelGGL(xsplit, dim3(xN / (256 * 4)), dim3(256), 0, stream, x, xhi, xlo);

  hipLaunchKernelGGL(lstm_rec, dim3(NWG), dim3(NTH), 0, stream,
                     xhi, xlo, Wf, bf, Wi, bi, Wg, bg, Wo, bo, hhi, hlo, hs,
                     arrive);

  hipLaunchKernelGGL(lstm_fc, dim3((Bz * Sz / 64) * (DOUT / 64)), dim3(256), 0, stream,
                     hs, Wfc, bfc, out);
}